// Round 1
// baseline (537.910 us; speedup 1.0000x reference)
//
#include <hip/hip_runtime.h>
#include <hip/hip_bf16.h>

// Problem constants
#define N_SERVICES 5825
#define N_FEAT     16384
#define EMB        64
#define BATCH      16384

#define MT         365                 // ceil(5825/16) M-tiles of 16 rows
#define KSTEPS     (N_FEAT / 32)       // 512 MFMA k-steps (K=32 each)
#define KSPLIT     8                   // split-K factor
#define KSTEPS_PER (KSTEPS / KSPLIT)   // 64 k-steps per wave

typedef __bf16 bf16x8 __attribute__((ext_vector_type(8)));
typedef float  f32x4  __attribute__((ext_vector_type(4)));
typedef unsigned short ushort_t;

__device__ __forceinline__ bf16x8 load_bfrag(const ushort_t* p) {
    uint4 v = *reinterpret_cast<const uint4*>(p);
    return __builtin_bit_cast(bf16x8, v);
}

__device__ __forceinline__ void atom_add_f32(float* p, float v) {
    __hip_atomic_fetch_add(p, v, __ATOMIC_RELAXED, __HIP_MEMORY_SCOPE_AGENT);
}

// ---------------------------------------------------------------------------
// Repack embedding [16384][64] fp32 -> bf16 B-fragments.
// Fragment layout for mfma_f32_16x16x32_bf16 B operand:
//   lane l, reg j holds B[k0 + (l>>4)*8 + j][n0 + (l&15)]
// Packed address: Bp[ ((ks*4 + nt)*64 + l)*8 + j ]   (16 B contiguous per lane)
// ---------------------------------------------------------------------------
__global__ __launch_bounds__(256) void pack_b(const float* __restrict__ B,
                                              ushort_t* __restrict__ Bp) {
    int t  = blockIdx.x * 256 + threadIdx.x;   // 0 .. 512*4*64-1 = 131071
    int l  = t & 63;
    int g  = t >> 6;            // ks*4 + nt
    int nt = g & 3;
    int ks = g >> 2;
    int col = nt * 16 + (l & 15);
    int kb  = ks * 32 + ((l >> 4) << 3);

    alignas(16) ushort_t u[8];
#pragma unroll
    for (int j = 0; j < 8; ++j) {
        float v = B[(size_t)(kb + j) * EMB + col];
        __bf16 h = (__bf16)v;
        u[j] = __builtin_bit_cast(ushort_t, h);
    }
    *reinterpret_cast<uint4*>(Bp + (size_t)t * 8) = *reinterpret_cast<const uint4*>(u);
}

// ---------------------------------------------------------------------------
// P[5840][64] += A_mtile @ B   (split-K, atomic combine)
// One wave (64 threads) per block: computes 16 rows x 64 cols over its K-chunk.
// A fragment: lane l, reg j = A[m0 + (l&15)][k0 + (l>>4)*8 + j]  (8 floats
// contiguous -> 2x float4, converted to bf16 in-reg).
// ---------------------------------------------------------------------------
__global__ __launch_bounds__(64) void gemm_proj(const float* __restrict__ A,
                                                const ushort_t* __restrict__ Bp,
                                                float* __restrict__ proj) {
    const int mt = blockIdx.x;
    const int kc = blockIdx.y;
    const int l  = threadIdx.x;

    int row = mt * 16 + (l & 15);
    if (row >= N_SERVICES) row = N_SERVICES - 1;   // clamp: padded rows never gathered

    const float*    Arow = A + (size_t)row * N_FEAT + ((l >> 4) << 3);
    const ushort_t* Bl   = Bp + (size_t)l * 8;

    f32x4 acc0 = {0.f, 0.f, 0.f, 0.f};
    f32x4 acc1 = {0.f, 0.f, 0.f, 0.f};
    f32x4 acc2 = {0.f, 0.f, 0.f, 0.f};
    f32x4 acc3 = {0.f, 0.f, 0.f, 0.f};

    const int ks0 = kc * KSTEPS_PER;
#pragma unroll 2
    for (int s = 0; s < KSTEPS_PER; ++s) {
        const int ks = ks0 + s;
        const float4 a0 = *reinterpret_cast<const float4*>(Arow + (size_t)ks * 32);
        const float4 a1 = *reinterpret_cast<const float4*>(Arow + (size_t)ks * 32 + 4);

        bf16x8 af;
        af[0] = (__bf16)a0.x; af[1] = (__bf16)a0.y;
        af[2] = (__bf16)a0.z; af[3] = (__bf16)a0.w;
        af[4] = (__bf16)a1.x; af[5] = (__bf16)a1.y;
        af[6] = (__bf16)a1.z; af[7] = (__bf16)a1.w;

        const size_t bbase = (size_t)(ks * 4) * 64 * 8;
        bf16x8 b0 = load_bfrag(Bl + bbase);
        bf16x8 b1 = load_bfrag(Bl + bbase + 1 * 64 * 8);
        bf16x8 b2 = load_bfrag(Bl + bbase + 2 * 64 * 8);
        bf16x8 b3 = load_bfrag(Bl + bbase + 3 * 64 * 8);

        acc0 = __builtin_amdgcn_mfma_f32_16x16x32_bf16(af, b0, acc0, 0, 0, 0);
        acc1 = __builtin_amdgcn_mfma_f32_16x16x32_bf16(af, b1, acc1, 0, 0, 0);
        acc2 = __builtin_amdgcn_mfma_f32_16x16x32_bf16(af, b2, acc2, 0, 0, 0);
        acc3 = __builtin_amdgcn_mfma_f32_16x16x32_bf16(af, b3, acc3, 0, 0, 0);
    }

    // C/D layout: col = lane&15, row = (lane>>4)*4 + reg
    const int orow = mt * 16 + ((l >> 4) << 2);
    const int ocol = l & 15;
    float* p = proj + (size_t)orow * EMB + ocol;
#pragma unroll
    for (int r = 0; r < 4; ++r) {
        atom_add_f32(p + (size_t)r * EMB,      acc0[r]);
        atom_add_f32(p + (size_t)r * EMB + 16, acc1[r]);
        atom_add_f32(p + (size_t)r * EMB + 32, acc2[r]);
        atom_add_f32(p + (size_t)r * EMB + 48, acc3[r]);
    }
}

// ---------------------------------------------------------------------------
// out[b][:] = P[data[b]][:]   (float4-vectorized gather; P is L2-resident)
// ---------------------------------------------------------------------------
__global__ __launch_bounds__(256) void gather_out(const int* __restrict__ data,
                                                  const float4* __restrict__ proj4,
                                                  float4* __restrict__ out4) {
    int t    = blockIdx.x * 256 + threadIdx.x;  // 0 .. BATCH*16-1
    int rowb = t >> 4;                          // batch index
    int c    = t & 15;                          // float4 column
    int s    = data[rowb];
    out4[t] = proj4[(size_t)s * 16 + c];
}

extern "C" void kernel_launch(void* const* d_in, const int* in_sizes, int n_in,
                              void* d_out, int out_size, void* d_ws, size_t ws_size,
                              hipStream_t stream) {
    const int*   data = (const int*)d_in[0];
    const float* A    = (const float*)d_in[1];   // service_matrix [5825][16384]
    const float* B    = (const float*)d_in[2];   // embedding      [16384][64]
    float*       out  = (float*)d_out;

    // workspace: proj [5840][64] f32 (1,495,040 B) then packed B bf16 (2 MiB)
    float*    proj = (float*)d_ws;
    ushort_t* Bp   = (ushort_t*)((char*)d_ws + (size_t)MT * 16 * EMB * sizeof(float));

    hipMemsetAsync(proj, 0, (size_t)MT * 16 * EMB * sizeof(float), stream);
    pack_b<<<512, 256, 0, stream>>>(B, Bp);
    gemm_proj<<<dim3(MT, KSPLIT), 64, 0, stream>>>(A, Bp, proj);
    gather_out<<<(BATCH * 16) / 256, 256, 0, stream>>>(data, (const float4*)proj,
                                                       (float4*)out);
}

// Round 3
// 531.405 us; speedup vs baseline: 1.0122x; 1.0122x over previous
//
#include <hip/hip_runtime.h>
#include <hip/hip_bf16.h>

// Problem constants
#define N_SERVICES 5825
#define N_FEAT     16384
#define EMB        64
#define BATCH      16384

#define MT         365                  // ceil(5825/16) M-tiles of 16 rows
#define KSTEPS     (N_FEAT / 32)        // 512 MFMA k-steps (K=32 each)
#define KSPLIT_G   8                    // grid-level split-K
#define WAVES      4                    // waves per block, each takes a K sub-chunk
#define KC_EFF     (KSPLIT_G * WAVES)   // 32 effective K-chunks
#define KSTEPS_PW  (KSTEPS / KC_EFF)    // 16 k-steps per wave

#define TILE_F     (16 * EMB)           // 1024 floats per output tile
#define PROJ_F     (MT * TILE_F)        // 373,760 floats in proj
#define PROJ_V4    (PROJ_F / 4)         // 93,440 float4

typedef __bf16 bf16x8 __attribute__((ext_vector_type(8)));
typedef float  f32x4  __attribute__((ext_vector_type(4)));
typedef unsigned short ushort_t;

__device__ __forceinline__ bf16x8 load_bfrag(const ushort_t* p) {
    uint4 v = *reinterpret_cast<const uint4*>(p);
    return __builtin_bit_cast(bf16x8, v);
}

// ---------------------------------------------------------------------------
// Repack embedding [16384][64] fp32 -> bf16 B-fragments.
//   lane l, reg j holds B[k0 + (l>>4)*8 + j][n0 + (l&15)]
// Packed address: Bp[ ((ks*4 + nt)*64 + l)*8 + j ]  (16 B contiguous per lane)
// ---------------------------------------------------------------------------
__global__ __launch_bounds__(256) void pack_b(const float* __restrict__ B,
                                              ushort_t* __restrict__ Bp) {
    int t  = blockIdx.x * 256 + threadIdx.x;   // 0 .. 512*4*64-1
    int l  = t & 63;
    int g  = t >> 6;            // ks*4 + nt
    int nt = g & 3;
    int ks = g >> 2;
    int col = nt * 16 + (l & 15);
    int kb  = ks * 32 + ((l >> 4) << 3);

    alignas(16) ushort_t u[8];
#pragma unroll
    for (int j = 0; j < 8; ++j) {
        float v = B[(size_t)(kb + j) * EMB + col];
        __bf16 h = (__bf16)v;
        u[j] = __builtin_bit_cast(ushort_t, h);
    }
    *reinterpret_cast<uint4*>(Bp + (size_t)t * 8) = *reinterpret_cast<const uint4*>(u);
}

// ---------------------------------------------------------------------------
// partial[kcg][mt tile] = A_mtile @ B over this block's K range.
// Block = 256 threads = 4 waves; wave w handles K-chunk (blockIdx.y*4 + w).
// All 4 waves compute the SAME 16x64 tile -> LDS reduce -> one coalesced
// 4 KB store per block. NO global atomics.
// ---------------------------------------------------------------------------
__global__ __launch_bounds__(256) void gemm_proj(const float* __restrict__ A,
                                                 const ushort_t* __restrict__ Bp,
                                                 float* __restrict__ partial) {
    __shared__ float lds[WAVES][TILE_F];   // 16 KB

    const int mt  = blockIdx.x;
    const int wid = threadIdx.x >> 6;
    const int l   = threadIdx.x & 63;
    const int kc  = blockIdx.y * WAVES + wid;

    int row = mt * 16 + (l & 15);
    if (row >= N_SERVICES) row = N_SERVICES - 1;   // clamp: pad rows never gathered

    const float*    Arow = A + (size_t)row * N_FEAT + ((l >> 4) << 3);
    const ushort_t* Bl   = Bp + (size_t)l * 8;

    f32x4 acc0 = {0.f, 0.f, 0.f, 0.f};
    f32x4 acc1 = {0.f, 0.f, 0.f, 0.f};
    f32x4 acc2 = {0.f, 0.f, 0.f, 0.f};
    f32x4 acc3 = {0.f, 0.f, 0.f, 0.f};

    const int ks0 = kc * KSTEPS_PW;
#pragma unroll 4
    for (int s = 0; s < KSTEPS_PW; ++s) {
        const int ks = ks0 + s;
        const float4 a0 = *reinterpret_cast<const float4*>(Arow + (size_t)ks * 32);
        const float4 a1 = *reinterpret_cast<const float4*>(Arow + (size_t)ks * 32 + 4);

        const size_t bbase = (size_t)(ks * 4) * 64 * 8;
        bf16x8 b0 = load_bfrag(Bl + bbase);
        bf16x8 b1 = load_bfrag(Bl + bbase + 1 * 64 * 8);
        bf16x8 b2 = load_bfrag(Bl + bbase + 2 * 64 * 8);
        bf16x8 b3 = load_bfrag(Bl + bbase + 3 * 64 * 8);

        bf16x8 af;
        af[0] = (__bf16)a0.x; af[1] = (__bf16)a0.y;
        af[2] = (__bf16)a0.z; af[3] = (__bf16)a0.w;
        af[4] = (__bf16)a1.x; af[5] = (__bf16)a1.y;
        af[6] = (__bf16)a1.z; af[7] = (__bf16)a1.w;

        acc0 = __builtin_amdgcn_mfma_f32_16x16x32_bf16(af, b0, acc0, 0, 0, 0);
        acc1 = __builtin_amdgcn_mfma_f32_16x16x32_bf16(af, b1, acc1, 0, 0, 0);
        acc2 = __builtin_amdgcn_mfma_f32_16x16x32_bf16(af, b2, acc2, 0, 0, 0);
        acc3 = __builtin_amdgcn_mfma_f32_16x16x32_bf16(af, b3, acc3, 0, 0, 0);
    }

    // C/D layout: col = lane&15, row_in_tile = (lane>>4)*4 + reg
    const int rbase = ((l >> 4) << 2);
    const int col   = l & 15;
#pragma unroll
    for (int r = 0; r < 4; ++r) {
        float* lp = &lds[wid][(rbase + r) * EMB + col];
        lp[0]  = acc0[r];
        lp[16] = acc1[r];
        lp[32] = acc2[r];
        lp[48] = acc3[r];
    }
    __syncthreads();

    // Reduce 4 waves -> one tile; 256 threads x float4 = 1024 floats
    const int t4 = threadIdx.x * 4;
    f32x4 s = *reinterpret_cast<const f32x4*>(&lds[0][t4]);
#pragma unroll
    for (int g = 1; g < WAVES; ++g)
        s += *reinterpret_cast<const f32x4*>(&lds[g][t4]);

    f32x4* out = reinterpret_cast<f32x4*>(partial) +
                 (size_t)blockIdx.y * PROJ_V4 + mt * (TILE_F / 4) + threadIdx.x;
    *out = s;
}

// ---------------------------------------------------------------------------
// proj[i] = sum over 8 grid-level K-slices of partial
// ---------------------------------------------------------------------------
__global__ __launch_bounds__(256) void reduce_proj(const f32x4* __restrict__ partial,
                                                   f32x4* __restrict__ proj) {
    int t = blockIdx.x * 256 + threadIdx.x;   // 0 .. PROJ_V4-1
    f32x4 s = partial[t];
#pragma unroll
    for (int g = 1; g < KSPLIT_G; ++g)
        s += partial[(size_t)g * PROJ_V4 + t];
    proj[t] = s;
}

// ---------------------------------------------------------------------------
// out[b][:] = proj[data[b]][:]   (float4 gather; proj is L2/L3-resident)
// ---------------------------------------------------------------------------
__global__ __launch_bounds__(256) void gather_out(const int* __restrict__ data,
                                                  const float4* __restrict__ proj4,
                                                  float4* __restrict__ out4) {
    int t    = blockIdx.x * 256 + threadIdx.x;  // 0 .. BATCH*16-1
    int rowb = t >> 4;
    int c    = t & 15;
    int s    = data[rowb];
    out4[t] = proj4[(size_t)s * 16 + c];
}

extern "C" void kernel_launch(void* const* d_in, const int* in_sizes, int n_in,
                              void* d_out, int out_size, void* d_ws, size_t ws_size,
                              hipStream_t stream) {
    const int*   data = (const int*)d_in[0];
    const float* A    = (const float*)d_in[1];   // service_matrix [5825][16384]
    const float* B    = (const float*)d_in[2];   // embedding      [16384][64]
    float*       out  = (float*)d_out;

    // workspace layout (all 16B aligned):
    //   proj    [373760] f32            @ 0          (1,495,040 B)
    //   Bp      [2 MiB]  bf16 frags     @ 1,495,040
    //   partial [8][373760] f32         @ 3,592,192  (11,960,320 B)
    float*    proj    = (float*)d_ws;
    ushort_t* Bp      = (ushort_t*)((char*)d_ws + 1495040);
    float*    partial = (float*)((char*)d_ws + 3592192);

    pack_b<<<512, 256, 0, stream>>>(B, Bp);
    gemm_proj<<<dim3(MT, KSPLIT_G), 256, 0, stream>>>(A, Bp, partial);
    reduce_proj<<<PROJ_V4 / 256, 256, 0, stream>>>((const f32x4*)partial,
                                                   (f32x4*)proj);
    gather_out<<<(BATCH * 16) / 256, 256, 0, stream>>>(data, (const float4*)proj,
                                                       (float4*)out);
}